// Round 1
// 3185.467 us; speedup vs baseline: 1.5386x; 1.5386x over previous
//
#include <hip/hip_runtime.h>

#define Bv 2
#define Tv 2048
#define Dv 1024
#define Hv 16
#define HDv 64
#define Lv 4
#define Vv 32000
#define DFFv 4096
#define BTv (Bv * Tv)

typedef __attribute__((ext_vector_type(8))) short bfrag_t;  // 8 x bf16 MFMA frag
typedef __attribute__((ext_vector_type(4))) float f4_t;

__device__ __forceinline__ unsigned short f2bf(float f) {
  union { float f; unsigned int u; } cv; cv.f = f;
  unsigned int u = cv.u;
  u += 0x7fffu + ((u >> 16) & 1u);
  return (unsigned short)(u >> 16);
}

// ---------- elementwise f32 -> bf16 ----------
__global__ __launch_bounds__(256) void k_cvt(const float* __restrict__ src,
                                             unsigned short* __restrict__ dst, int n4) {
  int i = blockIdx.x * 256 + threadIdx.x;
  if (i >= n4) return;
  float4 v = ((const float4*)src)[i];
  ushort4 o;
  o.x = f2bf(v.x); o.y = f2bf(v.y); o.z = f2bf(v.z); o.w = f2bf(v.w);
  ((ushort4*)dst)[i] = o;
}

// ---------- embedding gather (fp32 residual stream) ----------
__global__ __launch_bounds__(256) void k_embed(const int* __restrict__ idx,
                                               const float* __restrict__ emb,
                                               float* __restrict__ x) {
  int row = blockIdx.x;
  ((float4*)(x + (size_t)row * Dv))[threadIdx.x] =
      ((const float4*)(emb + (size_t)idx[row] * Dv))[threadIdx.x];
}

// ---------- transpose + convert: src R x C f32 -> dst C x R bf16 ----------
__global__ __launch_bounds__(256) void k_tcvt(const float* __restrict__ src,
                                              unsigned short* __restrict__ dst,
                                              int R, int C) {
  __shared__ float tile[32][33];
  int c0 = blockIdx.x * 32, r0 = blockIdx.y * 32;
  int tx = threadIdx.x & 31, ty = threadIdx.x >> 5;
#pragma unroll
  for (int i = 0; i < 32; i += 8)
    tile[ty + i][tx] = src[(size_t)(r0 + ty + i) * C + c0 + tx];
  __syncthreads();
#pragma unroll
  for (int i = 0; i < 32; i += 8)
    dst[(size_t)(c0 + ty + i) * R + r0 + tx] = f2bf(tile[tx][ty + i]);
}

// ---------- layernorm: f32 in, bf16 out (block per row, D=1024) ----------
__global__ __launch_bounds__(256) void k_ln(const float* __restrict__ x,
                                            const float* __restrict__ w,
                                            const float* __restrict__ b,
                                            unsigned short* __restrict__ out) {
  int row = blockIdx.x, tid = threadIdx.x;
  float4 v = ((const float4*)(x + (size_t)row * Dv))[tid];
  float s = v.x + v.y + v.z + v.w;
  float s2 = v.x * v.x + v.y * v.y + v.z * v.z + v.w * v.w;
#pragma unroll
  for (int off = 32; off > 0; off >>= 1) {
    s += __shfl_xor(s, off);
    s2 += __shfl_xor(s2, off);
  }
  __shared__ float rs[4], rq[4];
  int wv_ = tid >> 6;
  if ((tid & 63) == 0) { rs[wv_] = s; rq[wv_] = s2; }
  __syncthreads();
  s = rs[0] + rs[1] + rs[2] + rs[3];
  s2 = rq[0] + rq[1] + rq[2] + rq[3];
  float mean = s * (1.0f / Dv);
  float var = s2 * (1.0f / Dv) - mean * mean;
  float rstd = rsqrtf(var + 1e-5f);
  float4 wv4 = ((const float4*)w)[tid];
  float4 bv4 = ((const float4*)b)[tid];
  ushort4 o;
  o.x = f2bf((v.x - mean) * rstd * wv4.x + bv4.x);
  o.y = f2bf((v.y - mean) * rstd * wv4.y + bv4.y);
  o.z = f2bf((v.z - mean) * rstd * wv4.z + bv4.z);
  o.w = f2bf((v.w - mean) * rstd * wv4.w + bv4.w);
  ((ushort4*)(out + (size_t)row * Dv))[tid] = o;
}

// ---------- RoPE: fp32 q,k in -> bf16 out; q pre-scaled by 1/sqrt(HD) ----------
__global__ __launch_bounds__(256) void k_rope_cvt(const float* __restrict__ q,
                                                  const float* __restrict__ k,
                                                  unsigned short* __restrict__ qo,
                                                  unsigned short* __restrict__ ko) {
  int g = blockIdx.x * 256 + threadIdx.x;  // pair index, B*T*512 total
  int row = g >> 9;
  int p = g & 511;          // h*32 + i
  int t = row & (Tv - 1);
  int hi = p & 31;
  float freq = (float)exp((double)hi * -0.28782313662425572);  // -ln(10000)/32
  float ang = (float)t * freq;
  float sn, cs;
  sincosf(ang, &sn, &cs);
  size_t base = (size_t)row * Dv + (size_t)(p >> 5) * HDv + (size_t)hi * 2;
  float e = q[base], o = q[base + 1];
  qo[base] = f2bf((e * cs - o * sn) * 0.125f);   // 1/sqrt(64) folded into Q
  qo[base + 1] = f2bf((e * sn + o * cs) * 0.125f);
  e = k[base]; o = k[base + 1];
  ko[base] = f2bf(e * cs - o * sn);
  ko[base + 1] = f2bf(e * sn + o * cs);
}

// ---------- causal flash attention, bf16 MFMA, fp32 softmax, 64x64 tiles ----------
// q,k,v: bf16 (B*T, D) laid out [b*T+t][h*64+d]; q pre-scaled by 1/8. y: bf16 same layout.
// 4 waves; wave w owns q-rows w*16..w*16+15. LDS stride 72 (144B = 36 words, coprime-ish
// with 32 banks -> uniform bank spread for ds_read_b128).
#define AST 72
__global__ __launch_bounds__(256) void k_attn(const unsigned short* __restrict__ q,
                                              const unsigned short* __restrict__ k,
                                              const unsigned short* __restrict__ v,
                                              unsigned short* __restrict__ y) {
  int qt = blockIdx.x, h = blockIdx.y, b = blockIdx.z;
  __shared__ unsigned short Ks[64 * AST];  // K tile [key][d]
  __shared__ unsigned short Vt[64 * AST];  // V tile transposed [d][key]
  __shared__ unsigned short Ps[64 * AST];  // P tile [qrow][key] (per-wave rows)
  int tid = threadIdx.x;
  int lane = tid & 63, wave = tid >> 6;
  int lrow = lane & 15, lq = lane >> 4;

  // Q fragments: A-layout (row = lane&15, k-offset = (lane>>4)*8), held in regs.
  size_t qbase = ((size_t)(b * Tv + qt * 64 + wave * 16 + lrow)) * Dv + h * HDv + lq * 8;
  bfrag_t aq0 = *(const bfrag_t*)(q + qbase);
  bfrag_t aq1 = *(const bfrag_t*)(q + qbase + 32);

  f4_t zero = {0.f, 0.f, 0.f, 0.f};
  f4_t o[4] = {zero, zero, zero, zero};          // O cols dj*16+lrow, rows lq*4+r
  float m[4] = {-1e30f, -1e30f, -1e30f, -1e30f}; // per-row (lq*4+r) softmax state
  float l[4] = {0.f, 0.f, 0.f, 0.f};

  for (int kt = 0; kt <= qt; ++kt) {
    __syncthreads();  // previous iteration's Ks/Vt reads complete
    size_t kvbase = ((size_t)(b * Tv + kt * 64)) * Dv + h * HDv;
#pragma unroll
    for (int it = 0; it < 2; ++it) {
      int id = tid + 256 * it;        // 512 x 16B covers 64x64 bf16
      int key = id >> 3, d8 = (id & 7) * 8;
      *(bfrag_t*)&Ks[key * AST + d8] =
          *(const bfrag_t*)(k + kvbase + (size_t)key * Dv + d8);
      bfrag_t vv = *(const bfrag_t*)(v + kvbase + (size_t)key * Dv + d8);
#pragma unroll
      for (int j = 0; j < 8; ++j) Vt[(d8 + j) * AST + key] = (unsigned short)vv[j];
    }
    __syncthreads();

    // S = Q K^T : rows (wave*16 + lq*4 + r), cols (j*16 + lrow)
    f4_t sacc[4] = {zero, zero, zero, zero};
#pragma unroll
    for (int j = 0; j < 4; ++j) {
      bfrag_t kf0 = *(const bfrag_t*)&Ks[(j * 16 + lrow) * AST + lq * 8];
      bfrag_t kf1 = *(const bfrag_t*)&Ks[(j * 16 + lrow) * AST + 32 + lq * 8];
      sacc[j] = __builtin_amdgcn_mfma_f32_16x16x32_bf16(aq0, kf0, sacc[j], 0, 0, 0);
      sacc[j] = __builtin_amdgcn_mfma_f32_16x16x32_bf16(aq1, kf1, sacc[j], 0, 0, 0);
    }
    if (kt == qt) {
#pragma unroll
      for (int j = 0; j < 4; ++j)
#pragma unroll
        for (int r = 0; r < 4; ++r)
          if (lrow + 16 * j > wave * 16 + lq * 4 + r) sacc[j][r] = -1e30f;
    }

    // online softmax (fp32), P -> LDS as bf16
#pragma unroll
    for (int r = 0; r < 4; ++r) {
      float rmax = fmaxf(fmaxf(sacc[0][r], sacc[1][r]), fmaxf(sacc[2][r], sacc[3][r]));
#pragma unroll
      for (int msk = 1; msk < 16; msk <<= 1) rmax = fmaxf(rmax, __shfl_xor(rmax, msk));
      float mn = fmaxf(m[r], rmax);
      float alpha = expf(m[r] - mn);
      m[r] = mn;
      float psum = 0.f;
#pragma unroll
      for (int j = 0; j < 4; ++j) {
        float pv = expf(sacc[j][r] - mn);
        psum += pv;
        Ps[(wave * 16 + lq * 4 + r) * AST + lrow + 16 * j] = f2bf(pv);
      }
#pragma unroll
      for (int msk = 1; msk < 16; msk <<= 1) psum += __shfl_xor(psum, msk);
      l[r] = l[r] * alpha + psum;
      o[0][r] *= alpha; o[1][r] *= alpha; o[2][r] *= alpha; o[3][r] *= alpha;
    }
    __syncthreads();  // P visible across lanes (cross-lane within wave via LDS)

    // O += P V : A = P rows (this wave's 16), B = Vt rows (d)
    bfrag_t pf0 = *(const bfrag_t*)&Ps[(wave * 16 + lrow) * AST + lq * 8];
    bfrag_t pf1 = *(const bfrag_t*)&Ps[(wave * 16 + lrow) * AST + 32 + lq * 8];
#pragma unroll
    for (int dj = 0; dj < 4; ++dj) {
      bfrag_t vf0 = *(const bfrag_t*)&Vt[(dj * 16 + lrow) * AST + lq * 8];
      bfrag_t vf1 = *(const bfrag_t*)&Vt[(dj * 16 + lrow) * AST + 32 + lq * 8];
      o[dj] = __builtin_amdgcn_mfma_f32_16x16x32_bf16(pf0, vf0, o[dj], 0, 0, 0);
      o[dj] = __builtin_amdgcn_mfma_f32_16x16x32_bf16(pf1, vf1, o[dj], 0, 0, 0);
    }
  }

#pragma unroll
  for (int r = 0; r < 4; ++r) {
    float inv = 1.0f / l[r];
    size_t ybo = ((size_t)(b * Tv + qt * 64 + wave * 16 + lq * 4 + r)) * Dv + h * HDv;
#pragma unroll
    for (int dj = 0; dj < 4; ++dj)
      y[ybo + dj * 16 + lrow] = f2bf(o[dj][r] * inv);
  }
}

// ---------- bf16 MFMA GEMM: C(MxN) = A(MxK) * Bt(NxK)^T, fp32 acc ----------
// 128x128 tile, BK=32, 4 waves each 64x64 (4x4 of 16x16x32 MFMA).
template <bool BIAS, bool RES, bool GELU, bool OUTF32, bool OUTBF16>
__global__ __launch_bounds__(256) void k_gemm(const unsigned short* __restrict__ A,
                                              const unsigned short* __restrict__ Bt,
                                              const float* __restrict__ bias,
                                              float* __restrict__ C,
                                              unsigned short* __restrict__ Cb,
                                              int M, int N, int K) {
  __shared__ unsigned short As[128 * 40];  // stride 40 (+8 pad) keeps b128 reads 2-way max
  __shared__ unsigned short Bs[128 * 40];
  int tid = threadIdx.x;
  int n0 = blockIdx.x * 128, m0 = blockIdx.y * 128;
  int lane = tid & 63, wave = tid >> 6;
  int wm = (wave >> 1) * 64, wn = (wave & 1) * 64;
  int lrow = lane & 15, lq = lane >> 4;
  f4_t zero = {0.f, 0.f, 0.f, 0.f};
  f4_t acc[4][4];
#pragma unroll
  for (int i = 0; i < 4; ++i)
#pragma unroll
    for (int j = 0; j < 4; ++j) acc[i][j] = zero;
  int sr = tid >> 2, sq = (tid & 3) * 8;
  for (int kk = 0; kk < K; kk += 32) {
#pragma unroll
    for (int it = 0; it < 2; ++it) {
      int r = sr + it * 64;
      *(uint4*)(As + r * 40 + sq) = *(const uint4*)(A + (size_t)(m0 + r) * K + kk + sq);
      *(uint4*)(Bs + r * 40 + sq) = *(const uint4*)(Bt + (size_t)(n0 + r) * K + kk + sq);
    }
    __syncthreads();
    bfrag_t af[4], bfv[4];
#pragma unroll
    for (int i = 0; i < 4; ++i) {
      af[i] = *(const bfrag_t*)(As + (wm + i * 16 + lrow) * 40 + lq * 8);
      bfv[i] = *(const bfrag_t*)(Bs + (wn + i * 16 + lrow) * 40 + lq * 8);
    }
#pragma unroll
    for (int i = 0; i < 4; ++i)
#pragma unroll
      for (int j = 0; j < 4; ++j)
        acc[i][j] = __builtin_amdgcn_mfma_f32_16x16x32_bf16(af[i], bfv[j], acc[i][j], 0, 0, 0);
    __syncthreads();
  }
#pragma unroll
  for (int i = 0; i < 4; ++i) {
#pragma unroll
    for (int j = 0; j < 4; ++j) {
      int gc = n0 + wn + j * 16 + lrow;
      float bv = BIAS ? bias[gc] : 0.0f;
#pragma unroll
      for (int r = 0; r < 4; ++r) {
        int gr = m0 + wm + i * 16 + lq * 4 + r;
        float val = acc[i][j][r] + bv;
        if (GELU) val = 0.5f * val * (1.0f + erff(val * 0.70710678118654752f));
        size_t ci = (size_t)gr * N + gc;
        if (RES) val += C[ci];
        if (OUTF32) C[ci] = val;
        if (OUTBF16) Cb[ci] = f2bf(val);
      }
    }
  }
}

extern "C" void kernel_launch(void* const* d_in, const int* in_sizes, int n_in,
                              void* d_out, int out_size, void* d_ws, size_t ws_size,
                              hipStream_t stream) {
  const int* idx = (const int*)d_in[0];
  const float* tok = (const float*)d_in[1];
  const float* ln1w = (const float*)d_in[2];
  const float* ln1b = (const float*)d_in[3];
  const float* Wq = (const float*)d_in[4];
  const float* Wk = (const float*)d_in[5];
  const float* Wv = (const float*)d_in[6];
  const float* Wp = (const float*)d_in[7];
  const float* ln2w = (const float*)d_in[8];
  const float* ln2b = (const float*)d_in[9];
  const float* W1 = (const float*)d_in[10];
  const float* b1 = (const float*)d_in[11];
  const float* W2 = (const float*)d_in[12];
  const float* b2 = (const float*)d_in[13];
  const float* lnfw = (const float*)d_in[14];
  const float* lnfb = (const float*)d_in[15];
  float* out = (float*)d_out;

  char* ws = (char*)d_ws;
  size_t off = 0;
  auto alloc = [&](size_t bytes) -> void* {
    void* p = ws + off;
    off += (bytes + 255) & ~(size_t)255;
    return p;
  };
  float* x = (float*)alloc((size_t)BTv * Dv * 4);
  unsigned short* hb = (unsigned short*)alloc((size_t)BTv * Dv * 2);
  float* qb = (float*)alloc((size_t)BTv * Dv * 4);
  float* kb = (float*)alloc((size_t)BTv * Dv * 4);
  unsigned short* yb = (unsigned short*)alloc((size_t)BTv * Dv * 2);
  unsigned short* ub = (unsigned short*)alloc((size_t)BTv * DFFv * 2);
  unsigned short* wqt = (unsigned short*)alloc((size_t)Dv * Dv * 2);
  unsigned short* wkt = (unsigned short*)alloc((size_t)Dv * Dv * 2);
  unsigned short* wvt = (unsigned short*)alloc((size_t)Dv * Dv * 2);
  unsigned short* wpt = (unsigned short*)alloc((size_t)Dv * Dv * 2);
  unsigned short* w1t = (unsigned short*)alloc((size_t)DFFv * Dv * 2);
  unsigned short* w2t = (unsigned short*)alloc((size_t)Dv * DFFv * 2);
  unsigned short* embb = (unsigned short*)alloc((size_t)Vv * Dv * 2);
  // bf16 q/k/v alias the FFN buffer `ub`: lifetimes are disjoint on the serial
  // stream (qkv16 used rope->attn; ub used W1->W2 later in the layer).
  unsigned short* qb16 = ub;
  unsigned short* kb16 = ub + (size_t)BTv * Dv;
  unsigned short* vb16 = ub + (size_t)2 * BTv * Dv;

  k_cvt<<<(Vv * Dv / 4 + 255) / 256, 256, 0, stream>>>(tok, embb, Vv * Dv / 4);
  k_embed<<<BTv, 256, 0, stream>>>(idx, tok, x);
  for (int l = 0; l < Lv; ++l) {
    k_tcvt<<<dim3(Dv / 32, Dv / 32), 256, 0, stream>>>(Wq + (size_t)l * Dv * Dv, wqt, Dv, Dv);
    k_tcvt<<<dim3(Dv / 32, Dv / 32), 256, 0, stream>>>(Wk + (size_t)l * Dv * Dv, wkt, Dv, Dv);
    k_tcvt<<<dim3(Dv / 32, Dv / 32), 256, 0, stream>>>(Wv + (size_t)l * Dv * Dv, wvt, Dv, Dv);
    k_tcvt<<<dim3(Dv / 32, Dv / 32), 256, 0, stream>>>(Wp + (size_t)l * Dv * Dv, wpt, Dv, Dv);
    k_tcvt<<<dim3(DFFv / 32, Dv / 32), 256, 0, stream>>>(W1 + (size_t)l * Dv * DFFv, w1t, Dv, DFFv);
    k_tcvt<<<dim3(Dv / 32, DFFv / 32), 256, 0, stream>>>(W2 + (size_t)l * DFFv * Dv, w2t, DFFv, Dv);
    k_ln<<<BTv, 256, 0, stream>>>(x, ln1w + l * Dv, ln1b + l * Dv, hb);
    k_gemm<false, false, false, true, false><<<dim3(Dv / 128, BTv / 128), 256, 0, stream>>>(
        hb, wqt, nullptr, qb, nullptr, BTv, Dv, Dv);
    k_gemm<false, false, false, true, false><<<dim3(Dv / 128, BTv / 128), 256, 0, stream>>>(
        hb, wkt, nullptr, kb, nullptr, BTv, Dv, Dv);
    k_gemm<false, false, false, false, true><<<dim3(Dv / 128, BTv / 128), 256, 0, stream>>>(
        hb, wvt, nullptr, nullptr, vb16, BTv, Dv, Dv);
    k_rope_cvt<<<(BTv * 512) / 256, 256, 0, stream>>>(qb, kb, qb16, kb16);
    k_attn<<<dim3(Tv / 64, Hv, Bv), 256, 0, stream>>>(qb16, kb16, vb16, yb);
    k_gemm<false, true, false, true, false><<<dim3(Dv / 128, BTv / 128), 256, 0, stream>>>(
        yb, wpt, nullptr, x, nullptr, BTv, Dv, Dv);
    k_ln<<<BTv, 256, 0, stream>>>(x, ln2w + l * Dv, ln2b + l * Dv, hb);
    k_gemm<true, false, true, false, true><<<dim3(DFFv / 128, BTv / 128), 256, 0, stream>>>(
        hb, w1t, b1 + l * DFFv, nullptr, ub, BTv, DFFv, Dv);
    k_gemm<true, true, false, true, false><<<dim3(Dv / 128, BTv / 128), 256, 0, stream>>>(
        ub, w2t, b2 + l * Dv, x, nullptr, BTv, Dv, DFFv);
  }
  k_ln<<<BTv, 256, 0, stream>>>(x, lnfw, lnfb, hb);
  k_gemm<false, false, false, true, false><<<dim3(Vv / 128, BTv / 128), 256, 0, stream>>>(
      hb, embb, nullptr, out, nullptr, BTv, Vv, Dv);
  (void)in_sizes; (void)n_in; (void)out_size; (void)ws_size;
}

// Round 2
// 2928.626 us; speedup vs baseline: 1.6735x; 1.0877x over previous
//
#include <hip/hip_runtime.h>

#define Bv 2
#define Tv 2048
#define Dv 1024
#define Hv 16
#define HDv 64
#define Lv 4
#define Vv 32000
#define DFFv 4096
#define BTv (Bv * Tv)
#define D3v 3072

typedef __attribute__((ext_vector_type(8))) short bfrag_t;  // 8 x bf16 MFMA frag
typedef __attribute__((ext_vector_type(4))) float f4_t;

__device__ __forceinline__ unsigned short f2bf(float f) {
  union { float f; unsigned int u; } cv; cv.f = f;
  unsigned int u = cv.u;
  u += 0x7fffu + ((u >> 16) & 1u);
  return (unsigned short)(u >> 16);
}

// async global->LDS, 16B per lane. lds base must be wave-uniform; HW adds lane*16.
__device__ __forceinline__ void gload16(const void* g, void* l) {
  __builtin_amdgcn_global_load_lds((__attribute__((address_space(1))) void*)g,
                                   (__attribute__((address_space(3))) void*)l, 16, 0, 0);
}

// ---------- elementwise f32 -> bf16 ----------
__global__ __launch_bounds__(256) void k_cvt(const float* __restrict__ src,
                                             unsigned short* __restrict__ dst, int n4) {
  int i = blockIdx.x * 256 + threadIdx.x;
  if (i >= n4) return;
  float4 v = ((const float4*)src)[i];
  ushort4 o;
  o.x = f2bf(v.x); o.y = f2bf(v.y); o.z = f2bf(v.z); o.w = f2bf(v.w);
  ((ushort4*)dst)[i] = o;
}

// ---------- embedding gather (fp32 residual stream) ----------
__global__ __launch_bounds__(256) void k_embed(const int* __restrict__ idx,
                                               const float* __restrict__ emb,
                                               float* __restrict__ x) {
  int row = blockIdx.x;
  ((float4*)(x + (size_t)row * Dv))[threadIdx.x] =
      ((const float4*)(emb + (size_t)idx[row] * Dv))[threadIdx.x];
}

// ---------- transpose + convert: src R x C f32 -> dst C x R bf16 ----------
__global__ __launch_bounds__(256) void k_tcvt(const float* __restrict__ src,
                                              unsigned short* __restrict__ dst,
                                              int R, int C) {
  __shared__ float tile[32][33];
  int c0 = blockIdx.x * 32, r0 = blockIdx.y * 32;
  int tx = threadIdx.x & 31, ty = threadIdx.x >> 5;
#pragma unroll
  for (int i = 0; i < 32; i += 8)
    tile[ty + i][tx] = src[(size_t)(r0 + ty + i) * C + c0 + tx];
  __syncthreads();
#pragma unroll
  for (int i = 0; i < 32; i += 8)
    dst[(size_t)(c0 + ty + i) * R + r0 + tx] = f2bf(tile[tx][ty + i]);
}

// ---------- layernorm: f32 in, bf16 out (block per row, D=1024) ----------
__global__ __launch_bounds__(256) void k_ln(const float* __restrict__ x,
                                            const float* __restrict__ w,
                                            const float* __restrict__ b,
                                            unsigned short* __restrict__ out) {
  int row = blockIdx.x, tid = threadIdx.x;
  float4 v = ((const float4*)(x + (size_t)row * Dv))[tid];
  float s = v.x + v.y + v.z + v.w;
  float s2 = v.x * v.x + v.y * v.y + v.z * v.z + v.w * v.w;
#pragma unroll
  for (int off = 32; off > 0; off >>= 1) {
    s += __shfl_xor(s, off);
    s2 += __shfl_xor(s2, off);
  }
  __shared__ float rs[4], rq[4];
  int wv_ = tid >> 6;
  if ((tid & 63) == 0) { rs[wv_] = s; rq[wv_] = s2; }
  __syncthreads();
  s = rs[0] + rs[1] + rs[2] + rs[3];
  s2 = rq[0] + rq[1] + rq[2] + rq[3];
  float mean = s * (1.0f / Dv);
  float var = s2 * (1.0f / Dv) - mean * mean;
  float rstd = rsqrtf(var + 1e-5f);
  float4 wv4 = ((const float4*)w)[tid];
  float4 bv4 = ((const float4*)b)[tid];
  ushort4 o;
  o.x = f2bf((v.x - mean) * rstd * wv4.x + bv4.x);
  o.y = f2bf((v.y - mean) * rstd * wv4.y + bv4.y);
  o.z = f2bf((v.z - mean) * rstd * wv4.z + bv4.z);
  o.w = f2bf((v.w - mean) * rstd * wv4.w + bv4.w);
  ((ushort4*)(out + (size_t)row * Dv))[tid] = o;
}

// ---------- RoPE from fused qkv (f32, row stride 3072) -> bf16 q,k ----------
__global__ __launch_bounds__(256) void k_rope_cvt(const float* __restrict__ qkv,
                                                  unsigned short* __restrict__ qo,
                                                  unsigned short* __restrict__ ko) {
  int g = blockIdx.x * 256 + threadIdx.x;  // pair index, B*T*512 total
  int row = g >> 9;
  int p = g & 511;          // h*32 + i
  int t = row & (Tv - 1);
  int hi = p & 31;
  float freq = (float)exp((double)hi * -0.28782313662425572);  // -ln(10000)/32
  float ang = (float)t * freq;
  float sn, cs;
  sincosf(ang, &sn, &cs);
  size_t ibase = (size_t)row * D3v + (size_t)(p >> 5) * HDv + (size_t)hi * 2;
  size_t obase = (size_t)row * Dv + (size_t)(p >> 5) * HDv + (size_t)hi * 2;
  float e = qkv[ibase], o = qkv[ibase + 1];
  qo[obase] = f2bf((e * cs - o * sn) * 0.125f);   // 1/sqrt(64) folded into Q
  qo[obase + 1] = f2bf((e * sn + o * cs) * 0.125f);
  e = qkv[ibase + Dv]; o = qkv[ibase + Dv + 1];
  ko[obase] = f2bf(e * cs - o * sn);
  ko[obase + 1] = f2bf(e * sn + o * cs);
}

// ---------- V slice of fused qkv (f32 cols 2048..3071) -> bf16 ----------
__global__ __launch_bounds__(256) void k_vcvt(const float* __restrict__ qkv,
                                              unsigned short* __restrict__ vo) {
  int i = blockIdx.x * 256 + threadIdx.x;  // BTv*256 total, 4 floats each
  int row = i >> 8, c4 = (i & 255) * 4;
  float4 v = *(const float4*)(qkv + (size_t)row * D3v + 2 * Dv + c4);
  ushort4 o;
  o.x = f2bf(v.x); o.y = f2bf(v.y); o.z = f2bf(v.z); o.w = f2bf(v.w);
  *(ushort4*)(vo + (size_t)row * Dv + c4) = o;
}

// ---------- causal flash attention, bf16 MFMA, fp32 softmax, 64x64 tiles ----------
#define AST 72
__global__ __launch_bounds__(256) void k_attn(const unsigned short* __restrict__ q,
                                              const unsigned short* __restrict__ k,
                                              const unsigned short* __restrict__ v,
                                              unsigned short* __restrict__ y) {
  int qt = blockIdx.x, h = blockIdx.y, b = blockIdx.z;
  __shared__ unsigned short Ks[64 * AST];  // K tile [key][d]
  __shared__ unsigned short Vt[64 * AST];  // V tile transposed [d][key]
  __shared__ unsigned short Ps[64 * AST];  // P tile [qrow][key]
  int tid = threadIdx.x;
  int lane = tid & 63, wave = tid >> 6;
  int lrow = lane & 15, lq = lane >> 4;

  size_t qbase = ((size_t)(b * Tv + qt * 64 + wave * 16 + lrow)) * Dv + h * HDv + lq * 8;
  bfrag_t aq0 = *(const bfrag_t*)(q + qbase);
  bfrag_t aq1 = *(const bfrag_t*)(q + qbase + 32);

  f4_t zero = {0.f, 0.f, 0.f, 0.f};
  f4_t o[4] = {zero, zero, zero, zero};
  float m[4] = {-1e30f, -1e30f, -1e30f, -1e30f};
  float l[4] = {0.f, 0.f, 0.f, 0.f};

  for (int kt = 0; kt <= qt; ++kt) {
    __syncthreads();
    size_t kvbase = ((size_t)(b * Tv + kt * 64)) * Dv + h * HDv;
#pragma unroll
    for (int it = 0; it < 2; ++it) {
      int id = tid + 256 * it;        // 512 x 16B covers 64x64 bf16
      int key = id >> 3, d8 = (id & 7) * 8;
      *(bfrag_t*)&Ks[key * AST + d8] =
          *(const bfrag_t*)(k + kvbase + (size_t)key * Dv + d8);
      bfrag_t vv = *(const bfrag_t*)(v + kvbase + (size_t)key * Dv + d8);
#pragma unroll
      for (int j = 0; j < 8; ++j) Vt[(d8 + j) * AST + key] = (unsigned short)vv[j];
    }
    __syncthreads();

    f4_t sacc[4] = {zero, zero, zero, zero};
#pragma unroll
    for (int j = 0; j < 4; ++j) {
      bfrag_t kf0 = *(const bfrag_t*)&Ks[(j * 16 + lrow) * AST + lq * 8];
      bfrag_t kf1 = *(const bfrag_t*)&Ks[(j * 16 + lrow) * AST + 32 + lq * 8];
      sacc[j] = __builtin_amdgcn_mfma_f32_16x16x32_bf16(aq0, kf0, sacc[j], 0, 0, 0);
      sacc[j] = __builtin_amdgcn_mfma_f32_16x16x32_bf16(aq1, kf1, sacc[j], 0, 0, 0);
    }
    if (kt == qt) {
#pragma unroll
      for (int j = 0; j < 4; ++j)
#pragma unroll
        for (int r = 0; r < 4; ++r)
          if (lrow + 16 * j > wave * 16 + lq * 4 + r) sacc[j][r] = -1e30f;
    }

#pragma unroll
    for (int r = 0; r < 4; ++r) {
      float rmax = fmaxf(fmaxf(sacc[0][r], sacc[1][r]), fmaxf(sacc[2][r], sacc[3][r]));
#pragma unroll
      for (int msk = 1; msk < 16; msk <<= 1) rmax = fmaxf(rmax, __shfl_xor(rmax, msk));
      float mn = fmaxf(m[r], rmax);
      float alpha = expf(m[r] - mn);
      m[r] = mn;
      float psum = 0.f;
#pragma unroll
      for (int j = 0; j < 4; ++j) {
        float pv = expf(sacc[j][r] - mn);
        psum += pv;
        Ps[(wave * 16 + lq * 4 + r) * AST + lrow + 16 * j] = f2bf(pv);
      }
#pragma unroll
      for (int msk = 1; msk < 16; msk <<= 1) psum += __shfl_xor(psum, msk);
      l[r] = l[r] * alpha + psum;
      o[0][r] *= alpha; o[1][r] *= alpha; o[2][r] *= alpha; o[3][r] *= alpha;
    }
    __syncthreads();

    bfrag_t pf0 = *(const bfrag_t*)&Ps[(wave * 16 + lrow) * AST + lq * 8];
    bfrag_t pf1 = *(const bfrag_t*)&Ps[(wave * 16 + lrow) * AST + 32 + lq * 8];
#pragma unroll
    for (int dj = 0; dj < 4; ++dj) {
      bfrag_t vf0 = *(const bfrag_t*)&Vt[(dj * 16 + lrow) * AST + lq * 8];
      bfrag_t vf1 = *(const bfrag_t*)&Vt[(dj * 16 + lrow) * AST + 32 + lq * 8];
      o[dj] = __builtin_amdgcn_mfma_f32_16x16x32_bf16(pf0, vf0, o[dj], 0, 0, 0);
      o[dj] = __builtin_amdgcn_mfma_f32_16x16x32_bf16(pf1, vf1, o[dj], 0, 0, 0);
    }
  }

#pragma unroll
  for (int r = 0; r < 4; ++r) {
    float inv = 1.0f / l[r];
    size_t ybo = ((size_t)(b * Tv + qt * 64 + wave * 16 + lq * 4 + r)) * Dv + h * HDv;
#pragma unroll
    for (int dj = 0; dj < 4; ++dj)
      y[ybo + dj * 16 + lrow] = f2bf(o[dj][r] * inv);
  }
}

// ---------- bf16 MFMA GEMM: C(MxN) = A(MxK) * Bt(NxK)^T, fp32 acc ----------
// m97 structure: 128x128 tile, BK=32, linear LDS, width-16 global_load_lds staging.
// Block raster: bijective XCD swizzle (m204) + 8-wide n-panel supertiles for L2 reuse.
template <bool BIAS, bool RES, bool GELU, bool OUTF32, bool OUTBF16>
__global__ __launch_bounds__(256) void k_gemm(const unsigned short* __restrict__ A,
                                              const unsigned short* __restrict__ Bt,
                                              const float* __restrict__ bias,
                                              float* __restrict__ C,
                                              unsigned short* __restrict__ Cb,
                                              int M, int N, int K) {
  __shared__ unsigned short As[128 * 32];  // linear: row stride 32 shorts (64B)
  __shared__ unsigned short Bs[128 * 32];
  int tid = threadIdx.x;
  int lane = tid & 63, wave = tid >> 6;

  // ---- block swizzle ----
  int nbx = gridDim.x, nby = gridDim.y;
  int bid = blockIdx.y * nbx + blockIdx.x;
  int nwg = nbx * nby;
  int q8 = nwg >> 3, r8 = nwg & 7;
  int xcd = bid & 7, loc = bid >> 3;
  int swz = (xcd < r8 ? xcd * (q8 + 1) : r8 * (q8 + 1) + (xcd - r8) * q8) + loc;
  int panel = 8 * nby;             // blocks per full 8-wide n-panel
  int pid = swz / panel;
  int rem = swz - pid * panel;
  int pw = nbx - pid * 8; if (pw > 8) pw = 8;
  int mt = rem / pw;
  int nt = pid * 8 + rem - mt * pw;
  int n0 = nt * 128, m0 = mt * 128;

  int wm = (wave >> 1) * 64, wn = (wave & 1) * 64;
  int lrow = lane & 15, lq = lane >> 4;
  f4_t zero = {0.f, 0.f, 0.f, 0.f};
  f4_t acc[4][4];
#pragma unroll
  for (int i = 0; i < 4; ++i)
#pragma unroll
    for (int j = 0; j < 4; ++j) acc[i][j] = zero;

  int srow_l = lane >> 2;          // row-within-segment
  int sc = (lane & 3) * 8;         // col chunk (shorts)
  for (int kk = 0; kk < K; kk += 32) {
#pragma unroll
    for (int it = 0; it < 2; ++it) {
      int seg = wave + 4 * it;                 // 8 x 1KB segments per tile
      int srow = seg * 16 + srow_l;
      gload16(A + (size_t)(m0 + srow) * K + kk + sc, &As[seg * 512]);
      gload16(Bt + (size_t)(n0 + srow) * K + kk + sc, &Bs[seg * 512]);
    }
    __syncthreads();
    bfrag_t af[4], bfv[4];
#pragma unroll
    for (int i = 0; i < 4; ++i) {
      af[i] = *(const bfrag_t*)(As + (wm + i * 16 + lrow) * 32 + lq * 8);
      bfv[i] = *(const bfrag_t*)(Bs + (wn + i * 16 + lrow) * 32 + lq * 8);
    }
#pragma unroll
    for (int i = 0; i < 4; ++i)
#pragma unroll
      for (int j = 0; j < 4; ++j)
        acc[i][j] = __builtin_amdgcn_mfma_f32_16x16x32_bf16(af[i], bfv[j], acc[i][j], 0, 0, 0);
    __syncthreads();
  }
#pragma unroll
  for (int i = 0; i < 4; ++i) {
#pragma unroll
    for (int j = 0; j < 4; ++j) {
      int gc = n0 + wn + j * 16 + lrow;
      float bv = BIAS ? bias[gc] : 0.0f;
#pragma unroll
      for (int r = 0; r < 4; ++r) {
        int gr = m0 + wm + i * 16 + lq * 4 + r;
        float val = acc[i][j][r] + bv;
        if (GELU) val = 0.5f * val * (1.0f + erff(val * 0.70710678118654752f));
        size_t ci = (size_t)gr * N + gc;
        if (RES) val += C[ci];
        if (OUTF32) C[ci] = val;
        if (OUTBF16) Cb[ci] = f2bf(val);
      }
    }
  }
}

extern "C" void kernel_launch(void* const* d_in, const int* in_sizes, int n_in,
                              void* d_out, int out_size, void* d_ws, size_t ws_size,
                              hipStream_t stream) {
  const int* idx = (const int*)d_in[0];
  const float* tok = (const float*)d_in[1];
  const float* ln1w = (const float*)d_in[2];
  const float* ln1b = (const float*)d_in[3];
  const float* Wq = (const float*)d_in[4];
  const float* Wk = (const float*)d_in[5];
  const float* Wv = (const float*)d_in[6];
  const float* Wp = (const float*)d_in[7];
  const float* ln2w = (const float*)d_in[8];
  const float* ln2b = (const float*)d_in[9];
  const float* W1 = (const float*)d_in[10];
  const float* b1 = (const float*)d_in[11];
  const float* W2 = (const float*)d_in[12];
  const float* b2 = (const float*)d_in[13];
  const float* lnfw = (const float*)d_in[14];
  const float* lnfb = (const float*)d_in[15];
  float* out = (float*)d_out;

  char* ws = (char*)d_ws;
  size_t off = 0;
  auto alloc = [&](size_t bytes) -> void* {
    void* p = ws + off;
    off += (bytes + 255) & ~(size_t)255;
    return p;
  };
  float* x = (float*)alloc((size_t)BTv * Dv * 4);
  unsigned short* hb = (unsigned short*)alloc((size_t)BTv * Dv * 2);
  float* qkvb = (float*)alloc((size_t)BTv * D3v * 4);
  unsigned short* yb = (unsigned short*)alloc((size_t)BTv * Dv * 2);
  unsigned short* ub = (unsigned short*)alloc((size_t)BTv * DFFv * 2);
  unsigned short* wqkvt = (unsigned short*)alloc((size_t)D3v * Dv * 2);
  unsigned short* wpt = (unsigned short*)alloc((size_t)Dv * Dv * 2);
  unsigned short* w1t = (unsigned short*)alloc((size_t)DFFv * Dv * 2);
  unsigned short* w2t = (unsigned short*)alloc((size_t)Dv * DFFv * 2);
  unsigned short* embb = (unsigned short*)alloc((size_t)Vv * Dv * 2);
  // bf16 q/k/v alias the FFN buffer `ub` (disjoint lifetimes on serial stream)
  unsigned short* qb16 = ub;
  unsigned short* kb16 = ub + (size_t)BTv * Dv;
  unsigned short* vb16 = ub + (size_t)2 * BTv * Dv;

  k_cvt<<<(Vv * Dv / 4 + 255) / 256, 256, 0, stream>>>(tok, embb, Vv * Dv / 4);
  k_embed<<<BTv, 256, 0, stream>>>(idx, tok, x);
  for (int l = 0; l < Lv; ++l) {
    k_tcvt<<<dim3(Dv / 32, Dv / 32), 256, 0, stream>>>(Wq + (size_t)l * Dv * Dv,
                                                       wqkvt, Dv, Dv);
    k_tcvt<<<dim3(Dv / 32, Dv / 32), 256, 0, stream>>>(Wk + (size_t)l * Dv * Dv,
                                                       wqkvt + (size_t)Dv * Dv, Dv, Dv);
    k_tcvt<<<dim3(Dv / 32, Dv / 32), 256, 0, stream>>>(Wv + (size_t)l * Dv * Dv,
                                                       wqkvt + (size_t)2 * Dv * Dv, Dv, Dv);
    k_tcvt<<<dim3(Dv / 32, Dv / 32), 256, 0, stream>>>(Wp + (size_t)l * Dv * Dv, wpt, Dv, Dv);
    k_tcvt<<<dim3(DFFv / 32, Dv / 32), 256, 0, stream>>>(W1 + (size_t)l * Dv * DFFv, w1t, Dv, DFFv);
    k_tcvt<<<dim3(Dv / 32, DFFv / 32), 256, 0, stream>>>(W2 + (size_t)l * DFFv * Dv, w2t, DFFv, Dv);
    k_ln<<<BTv, 256, 0, stream>>>(x, ln1w + l * Dv, ln1b + l * Dv, hb);
    k_gemm<false, false, false, true, false><<<dim3(D3v / 128, BTv / 128), 256, 0, stream>>>(
        hb, wqkvt, nullptr, qkvb, nullptr, BTv, D3v, Dv);
    k_rope_cvt<<<(BTv * 512) / 256, 256, 0, stream>>>(qkvb, qb16, kb16);
    k_vcvt<<<BTv, 256, 0, stream>>>(qkvb, vb16);
    k_attn<<<dim3(Tv / 64, Hv, Bv), 256, 0, stream>>>(qb16, kb16, vb16, yb);
    k_gemm<false, true, false, true, false><<<dim3(Dv / 128, BTv / 128), 256, 0, stream>>>(
        yb, wpt, nullptr, x, nullptr, BTv, Dv, Dv);
    k_ln<<<BTv, 256, 0, stream>>>(x, ln2w + l * Dv, ln2b + l * Dv, hb);
    k_gemm<true, false, true, false, true><<<dim3(DFFv / 128, BTv / 128), 256, 0, stream>>>(
        hb, w1t, b1 + l * DFFv, nullptr, ub, BTv, DFFv, Dv);
    k_gemm<true, true, false, true, false><<<dim3(Dv / 128, BTv / 128), 256, 0, stream>>>(
        ub, w2t, b2 + l * Dv, x, nullptr, BTv, Dv, DFFv);
  }
  k_ln<<<BTv, 256, 0, stream>>>(x, lnfw, lnfb, hb);
  k_gemm<false, false, false, true, false><<<dim3(Vv / 128, BTv / 128), 256, 0, stream>>>(
      hb, embb, nullptr, out, nullptr, BTv, Vv, Dv);
  (void)in_sizes; (void)n_in; (void)out_size; (void)ws_size;
}